// Round 20
// baseline (257.736 us; speedup 1.0000x reference)
//
#include <hip/hip_runtime.h>
#include <cmath>

// B=64, L=512, H=64, 2H=128, OUT=5, VOC=32000
static constexpr int kB = 64, kL = 512, kH = 64, kH2 = 128, kOut = 5, kVoc = 32000;

typedef short bf16x8 __attribute__((ext_vector_type(8)));
typedef short s16x4  __attribute__((ext_vector_type(4)));
typedef float f32x4  __attribute__((ext_vector_type(4)));

__device__ __forceinline__ unsigned short f2bf(float f) {
  unsigned u = __float_as_uint(f);
  unsigned r = (u + 0x7FFFu + ((u >> 16) & 1u)) >> 16;   // RNE
  return (unsigned short)r;
}

__device__ __forceinline__ float bf2f(unsigned short u) {
  return __uint_as_float(((unsigned)u) << 16);
}

// ---- prepass: V -> bf16 vhi; W -> Wt bf16 [i][p]; embed -> bf16 ebf ----
__global__ void prep_k(const float* __restrict__ V, const float* __restrict__ W,
                       const float* __restrict__ embed,
                       unsigned short* __restrict__ vhi, unsigned short* __restrict__ wt,
                       unsigned short* __restrict__ ebf) {
  int idx = blockIdx.x * 256 + threadIdx.x;
  if (idx < kH * kH2 * kH2) { vhi[idx] = f2bf(V[idx]); return; }
  idx -= kH * kH2 * kH2;
  if (idx < kH * kH2) {
    int i = idx >> 7, p = idx & 127;
    wt[idx] = f2bf(W[p * kH + i]);         // Wt[i][p] = W[p][i]
    return;
  }
  idx -= kH * kH2;
  if (idx < kVoc * kH) ebf[idx] = f2bf(embed[idx]);
}

// ---- fused combine level: out[m,i] = tanh(c_m^T V_i c_m + (W^T c_m)_i + b_i)
// R16 math (bf16 chain, C-hi xVx, hi-only Wx — absmax-invariant) with a new
// work shape: 256-NODE TILES, 64 ROWS/WAVE (mt=0..3). Measured phase budget
// (R19): LDS reads were 6.1k of 7.2k cyc/phase — each wave re-read all of V
// for only 32 rows. Doubling rows/wave halves V-reads+stage per node, each
// V-fragment feeds 4 MFMAs, NO cross-wave combine (R13's failure mode).
// VGPR held ~160 by keeping Cred bf16-packed (unpack at the dot).
template<bool FIRST>
__global__ __launch_bounds__(256) void combine2_k(
    const unsigned short* __restrict__ inbf, const int* __restrict__ tokens,
    const unsigned short* __restrict__ vhi, const unsigned short* __restrict__ wt,
    const float* __restrict__ bias, unsigned short* __restrict__ outbf,
    int M, int IS)
{
  __shared__ unsigned short Vs[2][kH2 * kH2]; // 2 x 32 KB, XOR-swizzled chunks
  __shared__ float res[256 * 9];              // Wx+bias, then += xVx; IS<=8

  const int t = threadIdx.x;
  const int lane = t & 63, w = t >> 6;
  const int c = lane & 15, q = lane >> 4;    // c = m-col, q = quad (p-stripe)
  const int m0 = (int)blockIdx.x * 256;
  const int i0 = (int)blockIdx.y * IS;
  const int Mrows = (M < 256) ? M : 256;
  const bool has_rows = (w * 64) < Mrows;    // Mrows always multiple of 64

  bf16x8 bh[4][4];      // C bf16 B-fragments [mt][ks]        (64 VGPR)
  s16x4  cb[4][8];      // C bf16-packed for the p-dot [mt][pt] (64 VGPR)

  if (has_rows) {
    #pragma unroll
    for (int mt = 0; mt < 4; ++mt) {
      int m = m0 + w * 64 + mt * 16 + c;     // this lane's node row
      const unsigned short* brow = nullptr;
      int tokA = 0, tokB = 0;
      if (FIRST) {                           // level 1: gather from embed_bf
        int b = m >> 8, j = m & 255;         // Nout=256
        tokA = tokens[b * kL + 2 * j];
        tokB = tokens[b * kL + 2 * j + 1];
      } else {
        brow = inbf + (size_t)m * kH2;
      }
      #pragma unroll
      for (int ks = 0; ks < 4; ++ks) {       // B-frag: direct bf16 load
        int q0 = ks * 32 + q * 8;
        const unsigned short* bsrc = FIRST
            ? (inbf + (size_t)(q0 < 64 ? tokA : tokB) * kH + (q0 & 63))
            : (brow + q0);
        bh[mt][ks] = *(const bf16x8*)bsrc;
      }
      #pragma unroll
      for (int pt = 0; pt < 8; ++pt) {       // reduction copy: keep bf16-packed
        int p0 = pt * 16 + q * 4;
        const unsigned short* csrc = FIRST
            ? (inbf + (size_t)(p0 < 64 ? tokA : tokB) * kH + (p0 & 63))
            : (brow + p0);
        cb[mt][pt] = *(const s16x4*)csrc;
      }
    }
    // Wx GEMM (hi-only): res init = Wx + bias
    {
      int irow = i0 + c; if (irow > 63) irow = 63;
      f32x4 ah0 = {0.f,0.f,0.f,0.f}, ah1 = ah0, ah2 = ah0, ah3 = ah0;
      #pragma unroll
      for (int ks = 0; ks < 4; ++ks) {
        bf16x8 a = *(const bf16x8*)(wt + (size_t)irow * kH2 + ks * 32 + q * 8);
        ah0 = __builtin_amdgcn_mfma_f32_16x16x32_bf16(a, bh[0][ks], ah0, 0, 0, 0);
        ah1 = __builtin_amdgcn_mfma_f32_16x16x32_bf16(a, bh[1][ks], ah1, 0, 0, 0);
        ah2 = __builtin_amdgcn_mfma_f32_16x16x32_bf16(a, bh[2][ks], ah2, 0, 0, 0);
        ah3 = __builtin_amdgcn_mfma_f32_16x16x32_bf16(a, bh[3][ks], ah3, 0, 0, 0);
      }
      #pragma unroll
      for (int reg = 0; reg < 4; ++reg) {
        int ii = q * 4 + reg;                // i-row within tile
        if (ii < IS) {
          float bv = bias[i0 + ii];
          res[(w * 64 +  0 + c) * 9 + ii] = ah0[reg] + bv;
          res[(w * 64 + 16 + c) * 9 + ii] = ah1[reg] + bv;
          res[(w * 64 + 32 + c) * 9 + ii] = ah2[reg] + bv;
          res[(w * 64 + 48 + c) * 9 + ii] = ah3[reg] + bv;
        }
      }
    }
  }

  // V_i staging: XOR-chunk swizzle, global_load_lds width=16, wave-uniform dest
  auto stageV = [&](int i, int buf) {
    const unsigned short* vsrc = vhi + (size_t)i * (kH2 * kH2);
    #pragma unroll
    for (int r = 0; r < 8; ++r) {
      int chunk = w * 512 + r * 64 + lane;   // physical 16B chunk in LDS
      int p  = chunk >> 4;
      int pc = chunk & 15;
      int cc = pc ^ (p & 7);                 // logical chunk in V row p
      const unsigned short* g = vsrc + p * kH2 + cc * 8;
      __builtin_amdgcn_global_load_lds(
          (const __attribute__((address_space(1))) unsigned int*)g,
          (__attribute__((address_space(3))) unsigned int*)
              ((char*)&Vs[buf][0] + (size_t)(w * 512 + r * 64) * 16),
          16, 0, 0);
    }
  };

  // one ic's bilinear accumulation: each V-fragment feeds 4 MFMAs (mt 0..3)
  auto computeIC = [&](int ic, int buf) {
    const char* vbase = (const char*)&Vs[buf][0];
    float g0 = 0.f, g1 = 0.f, g2 = 0.f, g3 = 0.f;
    for (int pt = 0; pt < 8; ++pt) {
      int p = pt * 16 + c;                   // A-frag: V row p
      f32x4 a0 = {0.f,0.f,0.f,0.f}, a1 = a0, a2 = a0, a3 = a0;
      #pragma unroll
      for (int ks = 0; ks < 4; ++ks) {
        int cc = (ks * 4 + q) ^ (p & 7);     // swizzled chunk
        bf16x8 vf = *(const bf16x8*)(vbase + (size_t)p * 256 + cc * 16);
        a0 = __builtin_amdgcn_mfma_f32_16x16x32_bf16(vf, bh[0][ks], a0, 0, 0, 0);
        a1 = __builtin_amdgcn_mfma_f32_16x16x32_bf16(vf, bh[1][ks], a1, 0, 0, 0);
        a2 = __builtin_amdgcn_mfma_f32_16x16x32_bf16(vf, bh[2][ks], a2, 0, 0, 0);
        a3 = __builtin_amdgcn_mfma_f32_16x16x32_bf16(vf, bh[3][ks], a3, 0, 0, 0);
      }
      #pragma unroll
      for (int mt = 0; mt < 4; ++mt) {
        s16x4 cv = cb[mt][pt];
        float c0 = bf2f((unsigned short)cv[0]);
        float c1 = bf2f((unsigned short)cv[1]);
        float c2 = bf2f((unsigned short)cv[2]);
        float c3 = bf2f((unsigned short)cv[3]);
        f32x4 av = (mt == 0) ? a0 : (mt == 1) ? a1 : (mt == 2) ? a2 : a3;
        float* gp = (mt == 0) ? &g0 : (mt == 1) ? &g1 : (mt == 2) ? &g2 : &g3;
        float gg = *gp;
        gg = fmaf(c0, av[0], gg); gg = fmaf(c1, av[1], gg);
        gg = fmaf(c2, av[2], gg); gg = fmaf(c3, av[3], gg);
        *gp = gg;
      }
    }
    // sum over quads (p covers all 128 after this)
    g0 += __shfl_xor(g0, 16); g0 += __shfl_xor(g0, 32);
    g1 += __shfl_xor(g1, 16); g1 += __shfl_xor(g1, 32);
    g2 += __shfl_xor(g2, 16); g2 += __shfl_xor(g2, 32);
    g3 += __shfl_xor(g3, 16); g3 += __shfl_xor(g3, 32);
    float gq = (q == 0) ? g0 : (q == 1) ? g1 : (q == 2) ? g2 : g3;
    res[(w * 64 + q * 16 + c) * 9 + ic] += gq;   // quad q owns m-tile q
  };

  if (IS >= 2) {
    stageV(i0, 0); stageV(i0 + 1, 1);
    __syncthreads();
    for (int icp = 0; icp < IS; icp += 2) {
      if (has_rows) {
        computeIC(icp, 0);
        computeIC(icp + 1, 1);
      }
      __syncthreads();                        // V reads + res writes done
      if (icp + 2 < IS) {
        stageV(i0 + icp + 2, 0); stageV(i0 + icp + 3, 1);
        __syncthreads();
      }
    }
  } else {
    stageV(i0, 0);
    __syncthreads();
    if (has_rows) computeIC(0, 0);
    __syncthreads();
  }

  // epilogue: tanh + bf16 store only (next level consumes bf16)
  const int sh = __builtin_ctz(IS);
  for (int idx = t; idx < Mrows * IS; idx += 256) {
    int m = idx >> sh, ii = idx & (IS - 1);
    outbf[(size_t)(m0 + m) * kH + i0 + ii] = f2bf(tanhf(res[m * 9 + ii]));
  }
}

// ---- head: logits = root_bf @ Wout + bout; log_softmax ----
__global__ void head_k(const unsigned short* __restrict__ root,
                       const float* __restrict__ Wout,
                       const float* __restrict__ bout,
                       float* __restrict__ out) {
  int b = threadIdx.x;
  float l[kOut];
  #pragma unroll
  for (int o = 0; o < kOut; ++o) l[o] = bout[o];
  for (int h = 0; h < kH; ++h) {
    float r = bf2f(root[b * kH + h]);
    #pragma unroll
    for (int o = 0; o < kOut; ++o) l[o] = fmaf(r, Wout[h * kOut + o], l[o]);
  }
  float mx = l[0];
  #pragma unroll
  for (int o = 1; o < kOut; ++o) mx = fmaxf(mx, l[o]);
  float s = 0.f;
  #pragma unroll
  for (int o = 0; o < kOut; ++o) s += expf(l[o] - mx);
  float lse = logf(s);
  #pragma unroll
  for (int o = 0; o < kOut; ++o) out[b * kOut + o] = l[o] - mx - lse;
}

extern "C" void kernel_launch(void* const* d_in, const int* in_sizes, int n_in,
                              void* d_out, int out_size, void* d_ws, size_t ws_size,
                              hipStream_t stream) {
  const int*   tokens = (const int*)  d_in[0];
  const float* embed  = (const float*)d_in[1];
  const float* V      = (const float*)d_in[2];
  const float* W      = (const float*)d_in[3];
  const float* bias   = (const float*)d_in[4];
  const float* Wout   = (const float*)d_in[5];
  const float* bout   = (const float*)d_in[6];
  float* out = (float*)d_out;

  // ws layout (bytes): vhi 2MB | wt 16KB | ebf 4MB | bfA 2MB | bfB 1MB
  char* ws = (char*)d_ws;
  unsigned short* vhi = (unsigned short*)ws;
  unsigned short* wt  = (unsigned short*)(ws + 2097152);
  unsigned short* ebf = (unsigned short*)(ws + 2097152 + 16384);
  unsigned short* bfA = (unsigned short*)(ws + 2097152 + 16384 + 4194304);
  unsigned short* bfB = (unsigned short*)(ws + 2097152 + 16384 + 4194304 + 2097152);

  int nprep = kH * kH2 * kH2 + kH * kH2 + kVoc * kH;
  prep_k<<<dim3((nprep + 255) / 256), 256, 0, stream>>>(V, W, embed, vhi, wt, ebf);

  const unsigned short* cur = nullptr;
  unsigned short* nxt = bfA;
  bool first = true;
  for (int Nout = 256; Nout >= 1; Nout >>= 1) {
    int M = kB * Nout;
    int gx = (M + 255) / 256;                // 256-node tiles
    int IS = gx / 8; if (IS < 1) IS = 1; if (IS > 8) IS = 8;
    dim3 grid(gx, 64 / IS);
    if (first)
      combine2_k<true ><<<grid, 256, 0, stream>>>(ebf, tokens, vhi, wt, bias, nxt, M, IS);
    else
      combine2_k<false><<<grid, 256, 0, stream>>>(cur, nullptr, vhi, wt, bias, nxt, M, IS);
    first = false;
    cur = nxt;
    nxt = (nxt == bfA) ? bfB : bfA;
  }
  head_k<<<1, 64, 0, stream>>>(cur, Wout, bout, out);   // cur == bfA (9 levels)
}

// Round 21
// 204.566 us; speedup vs baseline: 1.2599x; 1.2599x over previous
//
#include <hip/hip_runtime.h>
#include <cmath>

// B=64, L=512, H=64, 2H=128, OUT=5, VOC=32000
static constexpr int kB = 64, kL = 512, kH = 64, kH2 = 128, kOut = 5, kVoc = 32000;

typedef short bf16x8 __attribute__((ext_vector_type(8)));
typedef short s16x4  __attribute__((ext_vector_type(4)));
typedef float f32x4  __attribute__((ext_vector_type(4)));

__device__ __forceinline__ unsigned short f2bf(float f) {
  unsigned u = __float_as_uint(f);
  unsigned r = (u + 0x7FFFu + ((u >> 16) & 1u)) >> 16;   // RNE
  return (unsigned short)r;
}

__device__ __forceinline__ float bf2f(unsigned short u) {
  return __uint_as_float(((unsigned)u) << 16);
}

// ---- prepass: V -> bf16 vhi; W -> Wt bf16 [i][p]; embed -> bf16 ebf ----
__global__ void prep_k(const float* __restrict__ V, const float* __restrict__ W,
                       const float* __restrict__ embed,
                       unsigned short* __restrict__ vhi, unsigned short* __restrict__ wt,
                       unsigned short* __restrict__ ebf) {
  int idx = blockIdx.x * 256 + threadIdx.x;
  if (idx < kH * kH2 * kH2) { vhi[idx] = f2bf(V[idx]); return; }
  idx -= kH * kH2 * kH2;
  if (idx < kH * kH2) {
    int i = idx >> 7, p = idx & 127;
    wt[idx] = f2bf(W[p * kH + i]);         // Wt[i][p] = W[p][i]
    return;
  }
  idx -= kH * kH2;
  if (idx < kVoc * kH) ebf[idx] = f2bf(embed[idx]);
}

// ---- fused combine level: out[m,i] = tanh(c_m^T V_i c_m + (W^T c_m)_i + b_i)
// SESSION-FINAL configuration (R16/R19, measured best: 205.7/206.1 µs):
//  - 128-node tiles, 4 waves, 2-ic double-buffered phases (R10)
//  - C-hi-only xVx (R11), hi-only Wx (R15) — absmax-invariant vs hi/lo
//  - fully bf16 inter-level chain; Cred unpacked bf16->fp32 by shift (R16)
// Falsified alternatives (counters in session log): dbuf-overlap (R1),
// occupancy>2blk/CU (R3/R17), VMEM pipe-split (R4/R7), grid fusion (R6),
// wave decompositions (R12/R13/R20), MFMA ILP (R14), tail bypass (R5/R17/R18).
// Floor: latency-bound at 2 waves/SIMD, no pipe >40%; 9 serialized levels.
template<bool FIRST>
__global__ __launch_bounds__(256) void combine2_k(
    const unsigned short* __restrict__ inbf, const int* __restrict__ tokens,
    const unsigned short* __restrict__ vhi, const unsigned short* __restrict__ wt,
    const float* __restrict__ bias, unsigned short* __restrict__ outbf,
    int M, int IS)
{
  __shared__ unsigned short Vs[2][kH2 * kH2]; // 2 x 32 KB, XOR-swizzled chunks
  __shared__ float res[128 * 17];             // Wx+bias, then += xVx; pad 17

  const int t = threadIdx.x;
  const int lane = t & 63, w = t >> 6;
  const int c = lane & 15, q = lane >> 4;    // c = B-col (node), q = quad
  const int m0 = (int)blockIdx.x * 128;
  const int i0 = (int)blockIdx.y * IS;
  const int Mrows = (M < 128) ? M : 128;
  const bool has_rows = (w * 32) < Mrows;

  bf16x8 bh[2][4];             // C bf16 B-fragments, [mtile][kstep]
  f32x4  Cred[2][8];           // C fp32 (from bf16) for the p-dot, [mt][pt]

  if (has_rows) {
    #pragma unroll
    for (int mt = 0; mt < 2; ++mt) {
      int m = m0 + w * 32 + mt * 16 + c;     // this lane's node row
      const unsigned short* brow = nullptr;
      int tokA = 0, tokB = 0;
      if (FIRST) {                           // level 1: gather from embed_bf
        int b = m >> 8, j = m & 255;         // Nout=256
        tokA = tokens[b * kL + 2 * j];
        tokB = tokens[b * kL + 2 * j + 1];
      } else {
        brow = inbf + (size_t)m * kH2;
      }
      #pragma unroll
      for (int ks = 0; ks < 4; ++ks) {       // B-frag: direct bf16 load
        int q0 = ks * 32 + q * 8;
        const unsigned short* bsrc = FIRST
            ? (inbf + (size_t)(q0 < 64 ? tokA : tokB) * kH + (q0 & 63))
            : (brow + q0);
        bh[mt][ks] = *(const bf16x8*)bsrc;
      }
      #pragma unroll
      for (int pt = 0; pt < 8; ++pt) {       // reduction copy: bf16 -> fp32
        int p0 = pt * 16 + q * 4;
        const unsigned short* csrc = FIRST
            ? (inbf + (size_t)(p0 < 64 ? tokA : tokB) * kH + (p0 & 63))
            : (brow + p0);
        s16x4 cv = *(const s16x4*)csrc;
        f32x4 cr;
        cr[0] = bf2f((unsigned short)cv[0]);
        cr[1] = bf2f((unsigned short)cv[1]);
        cr[2] = bf2f((unsigned short)cv[2]);
        cr[3] = bf2f((unsigned short)cv[3]);
        Cred[mt][pt] = cr;
      }
    }
    // Wx GEMM (hi-only): res init = Wx + bias
    {
      int irow = i0 + c; if (irow > 63) irow = 63;
      f32x4 ah0 = {0.f,0.f,0.f,0.f}, ah1 = ah0;
      #pragma unroll
      for (int ks = 0; ks < 4; ++ks) {
        bf16x8 a = *(const bf16x8*)(wt + (size_t)irow * kH2 + ks * 32 + q * 8);
        ah0 = __builtin_amdgcn_mfma_f32_16x16x32_bf16(a, bh[0][ks], ah0, 0, 0, 0);
        ah1 = __builtin_amdgcn_mfma_f32_16x16x32_bf16(a, bh[1][ks], ah1, 0, 0, 0);
      }
      #pragma unroll
      for (int reg = 0; reg < 4; ++reg) {
        int ii = q * 4 + reg;                // i-row within tile
        if (ii < IS) {
          float bv = bias[i0 + ii];
          res[(w * 32 + c) * 17 + ii]      = ah0[reg] + bv;
          res[(w * 32 + 16 + c) * 17 + ii] = ah1[reg] + bv;
        }
      }
    }
  }

  // V_i staging: XOR-chunk swizzle, global_load_lds width=16, wave-uniform dest
  auto stageV = [&](int i, int buf) {
    const unsigned short* vsrc = vhi + (size_t)i * (kH2 * kH2);
    #pragma unroll
    for (int r = 0; r < 8; ++r) {
      int chunk = w * 512 + r * 64 + lane;   // physical 16B chunk in LDS
      int p  = chunk >> 4;
      int pc = chunk & 15;
      int cc = pc ^ (p & 7);                 // logical chunk in V row p
      const unsigned short* g = vsrc + p * kH2 + cc * 8;
      __builtin_amdgcn_global_load_lds(
          (const __attribute__((address_space(1))) unsigned int*)g,
          (__attribute__((address_space(3))) unsigned int*)
              ((char*)&Vs[buf][0] + (size_t)(w * 512 + r * 64) * 16),
          16, 0, 0);
    }
  };

  // one ic's bilinear accumulation out of buffer `buf`
  auto computeIC = [&](int ic, int buf) {
    const char* vbase = (const char*)&Vs[buf][0];
    float g0 = 0.f, g1 = 0.f;
    for (int pt = 0; pt < 8; ++pt) {
      f32x4 a0 = {0.f,0.f,0.f,0.f}, a2 = a0;
      #pragma unroll
      for (int ks = 0; ks < 4; ++ks) {
        int p  = pt * 16 + c;                // A-frag: V row p, 8 bf16 at q-chunk
        int cc = (ks * 4 + q) ^ (p & 7);     // swizzled chunk
        bf16x8 vf = *(const bf16x8*)(vbase + (size_t)p * 256 + cc * 16);
        a0 = __builtin_amdgcn_mfma_f32_16x16x32_bf16(vf, bh[0][ks], a0, 0, 0, 0);
        a2 = __builtin_amdgcn_mfma_f32_16x16x32_bf16(vf, bh[1][ks], a2, 0, 0, 0);
      }
      f32x4 cr0 = Cred[0][pt], cr1 = Cred[1][pt];
      g0 = fmaf(cr0[0], a0[0], g0); g0 = fmaf(cr0[1], a0[1], g0);
      g0 = fmaf(cr0[2], a0[2], g0); g0 = fmaf(cr0[3], a0[3], g0);
      g1 = fmaf(cr1[0], a2[0], g1); g1 = fmaf(cr1[1], a2[1], g1);
      g1 = fmaf(cr1[2], a2[2], g1); g1 = fmaf(cr1[3], a2[3], g1);
    }
    // sum over quads (p covers all 128 after this)
    g0 += __shfl_xor(g0, 16); g0 += __shfl_xor(g0, 32);
    g1 += __shfl_xor(g1, 16); g1 += __shfl_xor(g1, 32);
    if (q == 0)      res[(w * 32 + c) * 17 + ic]      += g0;
    else if (q == 1) res[(w * 32 + 16 + c) * 17 + ic] += g1;
  };

  if (IS >= 2) {
    stageV(i0, 0); stageV(i0 + 1, 1);
    __syncthreads();
    for (int icp = 0; icp < IS; icp += 2) {
      if (has_rows) {
        computeIC(icp, 0);
        computeIC(icp + 1, 1);
      }
      __syncthreads();                        // V reads + res writes done
      if (icp + 2 < IS) {
        stageV(i0 + icp + 2, 0); stageV(i0 + icp + 3, 1);
        __syncthreads();
      }
    }
  } else {
    stageV(i0, 0);
    __syncthreads();
    if (has_rows) computeIC(0, 0);
    __syncthreads();
  }

  // epilogue: tanh + bf16 store only (next level consumes bf16)
  const int sh = __builtin_ctz(IS);
  for (int idx = t; idx < Mrows * IS; idx += 256) {
    int m = idx >> sh, ii = idx & (IS - 1);
    outbf[(size_t)(m0 + m) * kH + i0 + ii] = f2bf(tanhf(res[m * 17 + ii]));
  }
}

// ---- head: logits = root_bf @ Wout + bout; log_softmax ----
__global__ void head_k(const unsigned short* __restrict__ root,
                       const float* __restrict__ Wout,
                       const float* __restrict__ bout,
                       float* __restrict__ out) {
  int b = threadIdx.x;
  float l[kOut];
  #pragma unroll
  for (int o = 0; o < kOut; ++o) l[o] = bout[o];
  for (int h = 0; h < kH; ++h) {
    float r = bf2f(root[b * kH + h]);
    #pragma unroll
    for (int o = 0; o < kOut; ++o) l[o] = fmaf(r, Wout[h * kOut + o], l[o]);
  }
  float mx = l[0];
  #pragma unroll
  for (int o = 1; o < kOut; ++o) mx = fmaxf(mx, l[o]);
  float s = 0.f;
  #pragma unroll
  for (int o = 0; o < kOut; ++o) s += expf(l[o] - mx);
  float lse = logf(s);
  #pragma unroll
  for (int o = 0; o < kOut; ++o) out[b * kOut + o] = l[o] - mx - lse;
}

extern "C" void kernel_launch(void* const* d_in, const int* in_sizes, int n_in,
                              void* d_out, int out_size, void* d_ws, size_t ws_size,
                              hipStream_t stream) {
  const int*   tokens = (const int*)  d_in[0];
  const float* embed  = (const float*)d_in[1];
  const float* V      = (const float*)d_in[2];
  const float* W      = (const float*)d_in[3];
  const float* bias   = (const float*)d_in[4];
  const float* Wout   = (const float*)d_in[5];
  const float* bout   = (const float*)d_in[6];
  float* out = (float*)d_out;

  // ws layout (bytes): vhi 2MB | wt 16KB | ebf 4MB | bfA 2MB | bfB 1MB
  char* ws = (char*)d_ws;
  unsigned short* vhi = (unsigned short*)ws;
  unsigned short* wt  = (unsigned short*)(ws + 2097152);
  unsigned short* ebf = (unsigned short*)(ws + 2097152 + 16384);
  unsigned short* bfA = (unsigned short*)(ws + 2097152 + 16384 + 4194304);
  unsigned short* bfB = (unsigned short*)(ws + 2097152 + 16384 + 4194304 + 2097152);

  int nprep = kH * kH2 * kH2 + kH * kH2 + kVoc * kH;
  prep_k<<<dim3((nprep + 255) / 256), 256, 0, stream>>>(V, W, embed, vhi, wt, ebf);

  const unsigned short* cur = nullptr;
  unsigned short* nxt = bfA;
  bool first = true;
  for (int Nout = 256; Nout >= 1; Nout >>= 1) {
    int M = kB * Nout;
    int gx = (M + 127) / 128;
    int IS = gx / 8; if (IS < 1) IS = 1; if (IS > 16) IS = 16;
    dim3 grid(gx, 64 / IS);
    if (first)
      combine2_k<true ><<<grid, 256, 0, stream>>>(ebf, tokens, vhi, wt, bias, nxt, M, IS);
    else
      combine2_k<false><<<grid, 256, 0, stream>>>(cur, nullptr, vhi, wt, bias, nxt, M, IS);
    first = false;
    cur = nxt;
    nxt = (nxt == bfA) ? bfB : bfA;
  }
  head_k<<<1, 64, 0, stream>>>(cur, Wout, bout, out);   // cur == bfA (9 levels)
}